// Round 7
// baseline (1654.465 us; speedup 1.0000x reference)
//
#include <hip/hip_runtime.h>
#include <stdint.h>

#define B_    4
#define H_    16
#define S_    2048
#define D_    64
#define SCALE_LOG2E 0.1803368801111244f   // 0.125 * log2(e)

typedef __bf16 bf16x8 __attribute__((ext_vector_type(8)));
typedef __bf16 bf16x4 __attribute__((ext_vector_type(4)));
typedef float  f32x4  __attribute__((ext_vector_type(4)));

// ---- prep_k: K fp32 [bh][s][d] -> fragment-major bf16 image.
// Slice (bh, e, sb) = 4KB, chunk C = ksub*128 + kd*64 + lhi*16 + l15 (16B each):
//   holds K[bh][e*64 + sb*32 + ksub*16 + l15][kd*32 + lhi*8 + 0..7]  (contiguous in d)
__global__ __launch_bounds__(256)
void prep_k(const float* __restrict__ K, __bf16* __restrict__ img) {
    int t = blockIdx.x * 256 + threadIdx.x;      // 1,048,576 chunks
    int C = t & 255, slice = t >> 8;
    int sb = slice & 1, e = (slice >> 1) & 31, bh = slice >> 6;
    int l15 = C & 15, lhi = (C >> 4) & 3, kd = (C >> 6) & 1, ksub = C >> 7;
    const float* src = K + (((size_t)bh * S_ + e * 64 + sb * 32 + ksub * 16 + l15) * D_
                            + kd * 32 + lhi * 8);
    float4 a = *reinterpret_cast<const float4*>(src);
    float4 b = *reinterpret_cast<const float4*>(src + 4);
    bf16x8 w = { (__bf16)a.x,(__bf16)a.y,(__bf16)a.z,(__bf16)a.w,
                 (__bf16)b.x,(__bf16)b.y,(__bf16)b.z,(__bf16)b.w };
    *reinterpret_cast<bf16x8*>((char*)img + ((size_t)t << 4)) = w;
}

// ---- prep_v: V fp32 [bh][s][d] -> fragment-major transposed bf16 image.
// Slice (bh, e, sb) = 4KB, chunk C2 = db*64 + lhi*16 + l15:
//   w[j] = V[bh][e*64 + sb*32 + lhi*4 + (j&3) + (j>>2)*16][db*16 + l15]
__global__ __launch_bounds__(256)
void prep_v(const float* __restrict__ V, __bf16* __restrict__ img) {
    __shared__ float Ls[64][65];
    const int tid = threadIdx.x;
    const int bh = blockIdx.x >> 5, e = blockIdx.x & 31;
    const float* Vp = V + ((size_t)bh * S_ + e * 64) * D_;
    for (int i = tid; i < 1024; i += 256) {
        int r = i >> 4, c = (i & 15) << 2;
        float4 v = reinterpret_cast<const float4*>(Vp)[i];
        Ls[r][c] = v.x; Ls[r][c+1] = v.y; Ls[r][c+2] = v.z; Ls[r][c+3] = v.w;
    }
    __syncthreads();
    char* base = (char*)img + (size_t)(bh * 32 + e) * 8192;
    #pragma unroll
    for (int m = tid; m < 512; m += 256) {
        int sb = m >> 8, C2 = m & 255;
        int db = C2 >> 6, lhi = (C2 >> 4) & 3, l15 = C2 & 15;
        bf16x8 w;
        #pragma unroll
        for (int j = 0; j < 8; ++j)
            w[j] = (__bf16)Ls[sb * 32 + lhi * 4 + (j & 3) + ((j >> 2) << 4)][db * 16 + l15];
        *reinterpret_cast<bf16x8*>(base + sb * 4096 + C2 * 16) = w;
    }
}

// ---------- main: image-direct coalesced fragments, barrier-free hot loop ----------
__global__ __launch_bounds__(256, 4)
void sdpa_main(const float* __restrict__ Q, const __bf16* __restrict__ Kimg,
               const __bf16* __restrict__ Vimg, const int* __restrict__ mask,
               float* __restrict__ ctx_out, float* __restrict__ attn_out)
{
    __shared__ __align__(16) float shbuf[64 * 65];   // lsum scratch, then ctx reduce

    const int tid  = threadIdx.x;
    const int lane = tid & 63, wid = tid >> 6;
    const int l15  = lane & 15, lhi = lane >> 4;
    const int par  = wid & 1;        // tile parity this wave owns
    const int sb   = wid >> 1;       // 32-wide k-slice within tile

    const int orig = blockIdx.x, cpx = gridDim.x >> 3;
    const int bid  = (orig & 7) * cpx + (orig >> 3);
    const int qt = bid & 31, bh = bid >> 5, b = bh >> 4;

    const char* kimgT = (const char*)Kimg + (size_t)bh * 262144;
    const char* vimgT = (const char*)Vimg + (size_t)bh * 262144;

    // tile schedule: e = 2*((tt+qt)&15) + par  (16 tiles per wave)
    int etab[16];
    #pragma unroll
    for (int tt = 0; tt < 16; ++tt) etab[tt] = (((tt + qt) & 15) << 1) | par;

    // Q fragments as B-operand: lane l15 = q-col (rows qt*64 + rb*16 + l15)
    bf16x8 bQ[4][2];
    #pragma unroll
    for (int rb = 0; rb < 4; ++rb) {
        const float* qrow = Q + ((size_t)bh * S_ + qt * 64 + rb * 16 + l15) * D_ + lhi * 8;
        float4 a = *reinterpret_cast<const float4*>(qrow);
        float4 c = *reinterpret_cast<const float4*>(qrow + 4);
        bf16x8 w0 = { (__bf16)a.x,(__bf16)a.y,(__bf16)a.z,(__bf16)a.w,
                      (__bf16)c.x,(__bf16)c.y,(__bf16)c.z,(__bf16)c.w };
        bQ[rb][0] = w0;
        a = *reinterpret_cast<const float4*>(qrow + 32);
        c = *reinterpret_cast<const float4*>(qrow + 36);
        bf16x8 w1 = { (__bf16)a.x,(__bf16)a.y,(__bf16)a.z,(__bf16)a.w,
                      (__bf16)c.x,(__bf16)c.y,(__bf16)c.z,(__bf16)c.w };
        bQ[rb][1] = w1;
    }

    // mask bits: tile tt, ksub, r -> word tt>>2, bit (tt&3)*8 + ksub*4 + r (set = masked)
    uint32_t mwv[4] = {0, 0, 0, 0};
    {
        const int* mrow = mask + b * S_ + sb * 32 + lhi * 4;
        #pragma unroll
        for (int tt = 0; tt < 16; ++tt) {
            #pragma unroll
            for (int ksub = 0; ksub < 2; ++ksub) {
                int4 mm = *reinterpret_cast<const int4*>(mrow + etab[tt] * 64 + ksub * 16);
                uint32_t nib = (mm.x ? 1u : 0u) | (mm.y ? 2u : 0u) |
                               (mm.z ? 4u : 0u) | (mm.w ? 8u : 0u);
                mwv[tt >> 2] |= nib << (((tt & 3) * 8) + ksub * 4);
            }
        }
    }

    // K fragments: kf[buf][ksub][kd] — one contiguous coalesced b128 each
    bf16x8 kf[2][2][2];
    auto loadK = [&](int bufi, int tt) {
        const char* p = kimgT + (size_t)(etab[tt] * 2 + sb) * 4096 + lane * 16;
        kf[bufi][0][0] = *reinterpret_cast<const bf16x8*>(p);
        kf[bufi][0][1] = *reinterpret_cast<const bf16x8*>(p + 1024);
        kf[bufi][1][0] = *reinterpret_cast<const bf16x8*>(p + 2048);
        kf[bufi][1][1] = *reinterpret_cast<const bf16x8*>(p + 3072);
    };
    // V fragments: vv[buf][db] — direct PV B-operands, contiguous coalesced b128
    bf16x8 vv[2][4];
    auto loadV = [&](int bufi, int tt) {
        const char* p = vimgT + (size_t)(etab[tt] * 2 + sb) * 4096 + lane * 16;
        vv[bufi][0] = *reinterpret_cast<const bf16x8*>(p);
        vv[bufi][1] = *reinterpret_cast<const bf16x8*>(p + 1024);
        vv[bufi][2] = *reinterpret_cast<const bf16x8*>(p + 2048);
        vv[bufi][3] = *reinterpret_cast<const bf16x8*>(p + 3072);
    };

    // ---------------- pass 1: row sums ----------------
    float ls[4] = {0.f, 0.f, 0.f, 0.f};
    loadK(0, 0);
    #pragma unroll
    for (int tt = 0; tt < 16; ++tt) {
        if (tt + 1 < 16) loadK((tt + 1) & 1, tt + 1);
        const int cur = tt & 1;
        #pragma unroll
        for (int ksub = 0; ksub < 2; ++ksub) {
            uint32_t nib = (mwv[tt >> 2] >> (((tt & 3) * 8) + ksub * 4)) & 15u;
            #pragma unroll
            for (int rb = 0; rb < 4; ++rb) {
                f32x4 acc = {0.f, 0.f, 0.f, 0.f};
                acc = __builtin_amdgcn_mfma_f32_16x16x32_bf16(kf[cur][ksub][0], bQ[rb][0], acc, 0, 0, 0);
                acc = __builtin_amdgcn_mfma_f32_16x16x32_bf16(kf[cur][ksub][1], bQ[rb][1], acc, 0, 0, 0);
                float p0 = (nib & 1u) ? 0.f : exp2f(acc[0] * SCALE_LOG2E);
                float p1 = (nib & 2u) ? 0.f : exp2f(acc[1] * SCALE_LOG2E);
                float p2 = (nib & 4u) ? 0.f : exp2f(acc[2] * SCALE_LOG2E);
                float p3 = (nib & 8u) ? 0.f : exp2f(acc[3] * SCALE_LOG2E);
                ls[rb] += (p0 + p1) + (p2 + p3);
            }
        }
    }

    // reduce lsum: over lhi (shfl), then across 4 waves (LDS)
    #pragma unroll
    for (int rb = 0; rb < 4; ++rb) {
        ls[rb] += __shfl_xor(ls[rb], 16);
        ls[rb] += __shfl_xor(ls[rb], 32);
    }
    if (lhi == 0) {
        #pragma unroll
        for (int rb = 0; rb < 4; ++rb) shbuf[(wid * 4 + rb) * 16 + l15] = ls[rb];
    }
    __syncthreads();
    float rl[4];
    #pragma unroll
    for (int rb = 0; rb < 4; ++rb) {
        float tot = (shbuf[rb * 16 + l15] + shbuf[(4 + rb) * 16 + l15]) +
                    (shbuf[(8 + rb) * 16 + l15] + shbuf[(12 + rb) * 16 + l15]);
        rl[rb] = 1.0f / tot;
    }

    // ---------------- pass 2: attn store (full 128B lines) + PV ----------------
    f32x4 ctx[4][4];
    #pragma unroll
    for (int rb = 0; rb < 4; ++rb)
        #pragma unroll
        for (int db = 0; db < 4; ++db) ctx[rb][db] = (f32x4){0.f, 0.f, 0.f, 0.f};

    const size_t arowq = (size_t)bh * S_ + (size_t)qt * 64;

    loadK(0, 0); loadV(0, 0);
    bf16x4 pk[2][4];
    #pragma unroll
    for (int tt = 0; tt < 16; ++tt) {
        if (tt + 1 < 16) { loadK((tt + 1) & 1, tt + 1); loadV((tt + 1) & 1, tt + 1); }
        const int cur = tt & 1;
        const int e = etab[tt];
        const int colbase = e * 64 + sb * 32;
        // QK^T + exp + normalized store; the two ksub stores per row are adjacent instrs
        #pragma unroll
        for (int rb = 0; rb < 4; ++rb) {
            float* arow = attn_out + (arowq + rb * 16 + l15) * S_ + colbase + lhi * 4;
            #pragma unroll
            for (int ksub = 0; ksub < 2; ++ksub) {
                uint32_t nib = (mwv[tt >> 2] >> (((tt & 3) * 8) + ksub * 4)) & 15u;
                f32x4 acc = {0.f, 0.f, 0.f, 0.f};
                acc = __builtin_amdgcn_mfma_f32_16x16x32_bf16(kf[cur][ksub][0], bQ[rb][0], acc, 0, 0, 0);
                acc = __builtin_amdgcn_mfma_f32_16x16x32_bf16(kf[cur][ksub][1], bQ[rb][1], acc, 0, 0, 0);
                float p0 = (nib & 1u) ? 0.f : exp2f(acc[0] * SCALE_LOG2E) * rl[rb];
                float p1 = (nib & 2u) ? 0.f : exp2f(acc[1] * SCALE_LOG2E) * rl[rb];
                float p2 = (nib & 4u) ? 0.f : exp2f(acc[2] * SCALE_LOG2E) * rl[rb];
                float p3 = (nib & 8u) ? 0.f : exp2f(acc[3] * SCALE_LOG2E) * rl[rb];
                float4 st = { p0, p1, p2, p3 };
                *reinterpret_cast<float4*>(arow + ksub * 16) = st;
                bf16x4 pkk = { (__bf16)p0, (__bf16)p1, (__bf16)p2, (__bf16)p3 };
                pk[ksub][rb] = pkk;
            }
        }
        // PV: Av k-slot j <-> k_local = (j>>2)*16 + lhi*4 + (j&3), matching vv chunks
        #pragma unroll
        for (int db = 0; db < 4; ++db) {
            #pragma unroll
            for (int rb = 0; rb < 4; ++rb) {
                bf16x8 Av;
                Av[0]=pk[0][rb][0]; Av[1]=pk[0][rb][1]; Av[2]=pk[0][rb][2]; Av[3]=pk[0][rb][3];
                Av[4]=pk[1][rb][0]; Av[5]=pk[1][rb][1]; Av[6]=pk[1][rb][2]; Av[7]=pk[1][rb][3];
                ctx[rb][db] = __builtin_amdgcn_mfma_f32_16x16x32_bf16(Av, vv[cur][db], ctx[rb][db], 0, 0, 0);
            }
        }
    }

    // ---------------- cross-wave ctx reduce ----------------
    __syncthreads();
    for (int ph = 0; ph < 4; ++ph) {
        if (wid == ph) {
            #pragma unroll
            for (int rb = 0; rb < 4; ++rb)
                #pragma unroll
                for (int db = 0; db < 4; ++db)
                    #pragma unroll
                    for (int r = 0; r < 4; ++r) {
                        float* c = &shbuf[(rb * 16 + lhi * 4 + r) * 65 + db * 16 + l15];
                        if (ph == 0) *c = ctx[rb][db][r];
                        else         *c += ctx[rb][db][r];
                    }
        }
        __syncthreads();
    }
    for (int i = tid; i < 4096; i += 256) {
        int q = i >> 6, d = i & 63;
        ctx_out[(arowq + q) * D_ + d] = shbuf[q * 65 + d];
    }
}

extern "C" void kernel_launch(void* const* d_in, const int* in_sizes, int n_in,
                              void* d_out, int out_size, void* d_ws, size_t ws_size,
                              hipStream_t stream) {
    const float* Q    = (const float*)d_in[0];
    const float* K    = (const float*)d_in[1];
    const float* V    = (const float*)d_in[2];
    const int*   mask = (const int*)d_in[3];

    float* ctx_out  = (float*)d_out;
    float* attn_out = ctx_out + (size_t)B_ * H_ * S_ * D_;

    __bf16* Kimg = (__bf16*)d_ws;                              // 16.8 MB
    __bf16* Vimg = Kimg + (size_t)B_ * H_ * S_ * D_;           // 16.8 MB

    prep_k<<<4096, 256, 0, stream>>>(K, Kimg);
    prep_v<<<B_ * H_ * 32, 256, 0, stream>>>(V, Vimg);
    sdpa_main<<<B_ * H_ * 32, 256, 0, stream>>>(Q, Kimg, Vimg, mask, ctx_out, attn_out);
}

// Round 8
// 438.193 us; speedup vs baseline: 3.7757x; 3.7757x over previous
//
#include <hip/hip_runtime.h>
#include <stdint.h>

#define B_    4
#define H_    16
#define S_    2048
#define D_    64
#define SCALE_LOG2E 0.1803368801111244f   // 0.125 * log2(e)

typedef __bf16 bf16x8 __attribute__((ext_vector_type(8)));
typedef __bf16 bf16x4 __attribute__((ext_vector_type(4)));
typedef float  f32x4  __attribute__((ext_vector_type(4)));

// ---- prep_k: K fp32 [bh][s][d] -> fragment-major bf16 image.
// Slice (bh, e, sb) = 4KB, chunk C = ksub*128 + kd*64 + lhi*16 + l15 (16B each):
//   holds K[bh][e*64 + sb*32 + ksub*16 + l15][kd*32 + lhi*8 + 0..7]  (contiguous in d)
__global__ __launch_bounds__(256)
void prep_k(const float* __restrict__ K, __bf16* __restrict__ img) {
    int t = blockIdx.x * 256 + threadIdx.x;      // 1,048,576 chunks
    int C = t & 255, slice = t >> 8;
    int sb = slice & 1, e = (slice >> 1) & 31, bh = slice >> 6;
    int l15 = C & 15, lhi = (C >> 4) & 3, kd = (C >> 6) & 1, ksub = C >> 7;
    const float* src = K + (((size_t)bh * S_ + e * 64 + sb * 32 + ksub * 16 + l15) * D_
                            + kd * 32 + lhi * 8);
    float4 a = *reinterpret_cast<const float4*>(src);
    float4 b = *reinterpret_cast<const float4*>(src + 4);
    bf16x8 w = { (__bf16)a.x,(__bf16)a.y,(__bf16)a.z,(__bf16)a.w,
                 (__bf16)b.x,(__bf16)b.y,(__bf16)b.z,(__bf16)b.w };
    *reinterpret_cast<bf16x8*>((char*)img + ((size_t)t << 4)) = w;
}

// ---- prep_v: V fp32 [bh][s][d] -> fragment-major transposed bf16 image.
// Slice (bh, e, sb) = 4KB, chunk C2 = db*64 + lhi*16 + l15:
//   w[j] = V[bh][e*64 + sb*32 + lhi*4 + (j&3) + (j>>2)*16][db*16 + l15]
__global__ __launch_bounds__(256)
void prep_v(const float* __restrict__ V, __bf16* __restrict__ img) {
    __shared__ float Ls[64][65];
    const int tid = threadIdx.x;
    const int bh = blockIdx.x >> 5, e = blockIdx.x & 31;
    const float* Vp = V + ((size_t)bh * S_ + e * 64) * D_;
    for (int i = tid; i < 1024; i += 256) {
        int r = i >> 4, c = (i & 15) << 2;
        float4 v = reinterpret_cast<const float4*>(Vp)[i];
        Ls[r][c] = v.x; Ls[r][c+1] = v.y; Ls[r][c+2] = v.z; Ls[r][c+3] = v.w;
    }
    __syncthreads();
    char* base = (char*)img + (size_t)(bh * 32 + e) * 8192;
    #pragma unroll
    for (int m = tid; m < 512; m += 256) {
        int sb = m >> 8, C2 = m & 255;
        int db = C2 >> 6, lhi = (C2 >> 4) & 3, l15 = C2 & 15;
        bf16x8 w;
        #pragma unroll
        for (int j = 0; j < 8; ++j)
            w[j] = (__bf16)Ls[sb * 32 + lhi * 4 + (j & 3) + ((j >> 2) << 4)][db * 16 + l15];
        *reinterpret_cast<bf16x8*>(base + sb * 4096 + C2 * 16) = w;
    }
}

// ---------- main: image-direct coalesced fragments, barrier-free hot loop ----------
__global__ __launch_bounds__(256, 2)
void sdpa_main(const float* __restrict__ Q, const __bf16* __restrict__ Kimg,
               const __bf16* __restrict__ Vimg, const int* __restrict__ mask,
               float* __restrict__ ctx_out, float* __restrict__ attn_out)
{
    __shared__ __align__(16) float shbuf[64 * 65];   // lsum scratch, then ctx reduce

    const int tid  = threadIdx.x;
    const int lane = tid & 63, wid = tid >> 6;
    const int l15  = lane & 15, lhi = lane >> 4;
    const int par  = wid & 1;        // tile parity this wave owns
    const int sb   = wid >> 1;       // 32-wide k-slice within tile

    const int orig = blockIdx.x, cpx = gridDim.x >> 3;
    const int bid  = (orig & 7) * cpx + (orig >> 3);
    const int qt = bid & 31, bh = bid >> 5, b = bh >> 4;

    const char* kimgT = (const char*)Kimg + (size_t)bh * 262144;
    const char* vimgT = (const char*)Vimg + (size_t)bh * 262144;

    // Q fragments as B-operand, scale folded in: lane l15 = q-col
    bf16x8 bQ[4][2];
    #pragma unroll
    for (int rb = 0; rb < 4; ++rb) {
        const float* qrow = Q + ((size_t)bh * S_ + qt * 64 + rb * 16 + l15) * D_ + lhi * 8;
        float4 a = *reinterpret_cast<const float4*>(qrow);
        float4 c = *reinterpret_cast<const float4*>(qrow + 4);
        bf16x8 w0 = { (__bf16)(a.x*SCALE_LOG2E),(__bf16)(a.y*SCALE_LOG2E),
                      (__bf16)(a.z*SCALE_LOG2E),(__bf16)(a.w*SCALE_LOG2E),
                      (__bf16)(c.x*SCALE_LOG2E),(__bf16)(c.y*SCALE_LOG2E),
                      (__bf16)(c.z*SCALE_LOG2E),(__bf16)(c.w*SCALE_LOG2E) };
        bQ[rb][0] = w0;
        a = *reinterpret_cast<const float4*>(qrow + 32);
        c = *reinterpret_cast<const float4*>(qrow + 36);
        bf16x8 w1 = { (__bf16)(a.x*SCALE_LOG2E),(__bf16)(a.y*SCALE_LOG2E),
                      (__bf16)(a.z*SCALE_LOG2E),(__bf16)(a.w*SCALE_LOG2E),
                      (__bf16)(c.x*SCALE_LOG2E),(__bf16)(c.y*SCALE_LOG2E),
                      (__bf16)(c.z*SCALE_LOG2E),(__bf16)(c.w*SCALE_LOG2E) };
        bQ[rb][1] = w1;
    }

    // mask bits: tile tt, ksub, r -> word tt>>2, bit (tt&3)*8 + ksub*4 + r (set = masked)
    uint32_t mwv[4] = {0, 0, 0, 0};
    {
        const int* mrow = mask + b * S_ + sb * 32 + lhi * 4;
        #pragma unroll
        for (int tt = 0; tt < 16; ++tt) {
            int e = (((tt + qt) & 15) << 1) | par;
            #pragma unroll
            for (int ksub = 0; ksub < 2; ++ksub) {
                int4 mm = *reinterpret_cast<const int4*>(mrow + e * 64 + ksub * 16);
                uint32_t nib = (mm.x ? 1u : 0u) | (mm.y ? 2u : 0u) |
                               (mm.z ? 4u : 0u) | (mm.w ? 8u : 0u);
                mwv[tt >> 2] |= nib << (((tt & 3) * 8) + ksub * 4);
            }
        }
    }

    // K fragments: kf[buf][ksub][kd] — one contiguous coalesced b128 each
    bf16x8 kf[2][2][2];
    auto loadK = [&](int bufi, int tt) {
        int e = (((tt + qt) & 15) << 1) | par;
        const char* p = kimgT + (size_t)(e * 2 + sb) * 4096 + lane * 16;
        kf[bufi][0][0] = *reinterpret_cast<const bf16x8*>(p);
        kf[bufi][0][1] = *reinterpret_cast<const bf16x8*>(p + 1024);
        kf[bufi][1][0] = *reinterpret_cast<const bf16x8*>(p + 2048);
        kf[bufi][1][1] = *reinterpret_cast<const bf16x8*>(p + 3072);
    };
    // V fragments: vv[buf][db] — direct PV B-operands, contiguous coalesced b128
    bf16x8 vv[2][4];
    auto loadV = [&](int bufi, int tt) {
        int e = (((tt + qt) & 15) << 1) | par;
        const char* p = vimgT + (size_t)(e * 2 + sb) * 4096 + lane * 16;
        vv[bufi][0] = *reinterpret_cast<const bf16x8*>(p);
        vv[bufi][1] = *reinterpret_cast<const bf16x8*>(p + 1024);
        vv[bufi][2] = *reinterpret_cast<const bf16x8*>(p + 2048);
        vv[bufi][3] = *reinterpret_cast<const bf16x8*>(p + 3072);
    };

    // ---------------- pass 1: row sums ----------------
    float ls[4] = {0.f, 0.f, 0.f, 0.f};
    loadK(0, 0);
    #pragma unroll
    for (int tt = 0; tt < 16; ++tt) {
        if (tt + 1 < 16) loadK((tt + 1) & 1, tt + 1);
        const int cur = tt & 1;
        #pragma unroll
        for (int ksub = 0; ksub < 2; ++ksub) {
            uint32_t nib = (mwv[tt >> 2] >> (((tt & 3) * 8) + ksub * 4)) & 15u;
            #pragma unroll
            for (int rb = 0; rb < 4; ++rb) {
                f32x4 acc = {0.f, 0.f, 0.f, 0.f};
                acc = __builtin_amdgcn_mfma_f32_16x16x32_bf16(kf[cur][ksub][0], bQ[rb][0], acc, 0, 0, 0);
                acc = __builtin_amdgcn_mfma_f32_16x16x32_bf16(kf[cur][ksub][1], bQ[rb][1], acc, 0, 0, 0);
                float p0 = (nib & 1u) ? 0.f : exp2f(acc[0]);
                float p1 = (nib & 2u) ? 0.f : exp2f(acc[1]);
                float p2 = (nib & 4u) ? 0.f : exp2f(acc[2]);
                float p3 = (nib & 8u) ? 0.f : exp2f(acc[3]);
                ls[rb] += (p0 + p1) + (p2 + p3);
            }
        }
    }

    // reduce lsum: over lhi (shfl), then across 4 waves (LDS)
    #pragma unroll
    for (int rb = 0; rb < 4; ++rb) {
        ls[rb] += __shfl_xor(ls[rb], 16);
        ls[rb] += __shfl_xor(ls[rb], 32);
    }
    if (lhi == 0) {
        #pragma unroll
        for (int rb = 0; rb < 4; ++rb) shbuf[(wid * 4 + rb) * 16 + l15] = ls[rb];
    }
    __syncthreads();
    float rl[4];
    #pragma unroll
    for (int rb = 0; rb < 4; ++rb) {
        float tot = (shbuf[rb * 16 + l15] + shbuf[(4 + rb) * 16 + l15]) +
                    (shbuf[(8 + rb) * 16 + l15] + shbuf[(12 + rb) * 16 + l15]);
        rl[rb] = 1.0f / tot;
    }

    // ---------------- pass 2: attn store (full 128B lines) + PV ----------------
    f32x4 ctx[4][4];
    #pragma unroll
    for (int rb = 0; rb < 4; ++rb)
        #pragma unroll
        for (int db = 0; db < 4; ++db) ctx[rb][db] = (f32x4){0.f, 0.f, 0.f, 0.f};

    const size_t arowq = (size_t)bh * S_ + (size_t)qt * 64;

    loadK(0, 0); loadV(0, 0);
    bf16x4 pk[2][4];
    #pragma unroll
    for (int tt = 0; tt < 16; ++tt) {
        if (tt + 1 < 16) { loadK((tt + 1) & 1, tt + 1); loadV((tt + 1) & 1, tt + 1); }
        const int cur = tt & 1;
        const int e = (((tt + qt) & 15) << 1) | par;
        const int colbase = e * 64 + sb * 32;
        // QK^T + exp + normalized store; the two ksub stores per row are adjacent instrs
        #pragma unroll
        for (int rb = 0; rb < 4; ++rb) {
            float* arow = attn_out + (arowq + rb * 16 + l15) * S_ + colbase + lhi * 4;
            #pragma unroll
            for (int ksub = 0; ksub < 2; ++ksub) {
                uint32_t nib = (mwv[tt >> 2] >> (((tt & 3) * 8) + ksub * 4)) & 15u;
                f32x4 acc = {0.f, 0.f, 0.f, 0.f};
                acc = __builtin_amdgcn_mfma_f32_16x16x32_bf16(kf[cur][ksub][0], bQ[rb][0], acc, 0, 0, 0);
                acc = __builtin_amdgcn_mfma_f32_16x16x32_bf16(kf[cur][ksub][1], bQ[rb][1], acc, 0, 0, 0);
                float p0 = (nib & 1u) ? 0.f : exp2f(acc[0]) * rl[rb];
                float p1 = (nib & 2u) ? 0.f : exp2f(acc[1]) * rl[rb];
                float p2 = (nib & 4u) ? 0.f : exp2f(acc[2]) * rl[rb];
                float p3 = (nib & 8u) ? 0.f : exp2f(acc[3]) * rl[rb];
                float4 st = { p0, p1, p2, p3 };
                *reinterpret_cast<float4*>(arow + ksub * 16) = st;
                bf16x4 pkk = { (__bf16)p0, (__bf16)p1, (__bf16)p2, (__bf16)p3 };
                pk[ksub][rb] = pkk;
            }
        }
        // PV: Av k-slot j <-> k_local = (j>>2)*16 + lhi*4 + (j&3), matching vv chunks
        #pragma unroll
        for (int db = 0; db < 4; ++db) {
            #pragma unroll
            for (int rb = 0; rb < 4; ++rb) {
                bf16x8 Av;
                Av[0]=pk[0][rb][0]; Av[1]=pk[0][rb][1]; Av[2]=pk[0][rb][2]; Av[3]=pk[0][rb][3];
                Av[4]=pk[1][rb][0]; Av[5]=pk[1][rb][1]; Av[6]=pk[1][rb][2]; Av[7]=pk[1][rb][3];
                ctx[rb][db] = __builtin_amdgcn_mfma_f32_16x16x32_bf16(Av, vv[cur][db], ctx[rb][db], 0, 0, 0);
            }
        }
    }

    // ---------------- cross-wave ctx reduce ----------------
    __syncthreads();
    for (int ph = 0; ph < 4; ++ph) {
        if (wid == ph) {
            #pragma unroll
            for (int rb = 0; rb < 4; ++rb)
                #pragma unroll
                for (int db = 0; db < 4; ++db)
                    #pragma unroll
                    for (int r = 0; r < 4; ++r) {
                        float* c = &shbuf[(rb * 16 + lhi * 4 + r) * 65 + db * 16 + l15];
                        if (ph == 0) *c = ctx[rb][db][r];
                        else         *c += ctx[rb][db][r];
                    }
        }
        __syncthreads();
    }
    for (int i = tid; i < 4096; i += 256) {
        int q = i >> 6, d = i & 63;
        ctx_out[(arowq + q) * D_ + d] = shbuf[q * 65 + d];
    }
}

extern "C" void kernel_launch(void* const* d_in, const int* in_sizes, int n_in,
                              void* d_out, int out_size, void* d_ws, size_t ws_size,
                              hipStream_t stream) {
    const float* Q    = (const float*)d_in[0];
    const float* K    = (const float*)d_in[1];
    const float* V    = (const float*)d_in[2];
    const int*   mask = (const int*)d_in[3];

    float* ctx_out  = (float*)d_out;
    float* attn_out = ctx_out + (size_t)B_ * H_ * S_ * D_;

    __bf16* Kimg = (__bf16*)d_ws;                              // 16.8 MB
    __bf16* Vimg = Kimg + (size_t)B_ * H_ * S_ * D_;           // 16.8 MB

    prep_k<<<4096, 256, 0, stream>>>(K, Kimg);
    prep_v<<<B_ * H_ * 32, 256, 0, stream>>>(V, Vimg);
    sdpa_main<<<B_ * H_ * 32, 256, 0, stream>>>(Q, Kimg, Vimg, mask, ctx_out, attn_out);
}